// Round 6
// baseline (106.587 us; speedup 1.0000x reference)
//
#include <hip/hip_runtime.h>
#include <hip/hip_bf16.h>

#define BB 4
#define NN 2048
#define FIN 128
#define NH 4
#define DH 32
#define NS 0.2f

typedef unsigned int u32;
typedef unsigned short u16;
typedef unsigned long long u64;
typedef __attribute__((ext_vector_type(8))) short short8;
typedef __attribute__((ext_vector_type(4))) float f32x4;

// ws float offsets
#define OFF_ES 0          // [16][2048]
#define OFF_ED 32768      // [16][2048]
#define OFF_P  65536      // [16][2048]
#define OFF_Q  98304      // [16][2048]
#define OFF_M  131072     // [16]
#define OFF_HT 131088     // u16 [16][32][2048] = 1048576 u16 = 524288 floats
#define OFF_BITS 655376   // u32 [4][2048][64] = 524288 u32 (= OFF_HT + 524288)

__device__ __forceinline__ u16 f2bf_rne(float f) {
  unsigned u = __float_as_uint(f);
  return (u16)((u + 0x7fffu + ((u >> 16) & 1u)) >> 16);
}

// ---------------- K0: fused adj->bits pack (4/5 blocks) + projection (1/5) --
__global__ __launch_bounds__(256) void k_pp(
    const int* __restrict__ adj, u32* __restrict__ bits,
    const float* __restrict__ x, const float* __restrict__ W,
    const float* __restrict__ a, u16* __restrict__ hT,
    float* __restrict__ e_src, float* __restrict__ e_dst) {
  __shared__ float Ws[FIN * 128];  // used by proj role only (64 KB)
  const int bid = blockIdx.x;
  const int tid = threadIdx.x;

  if (bid % 5 != 0) {
    // ---- pack role: pid in [0,2048), 4 adj rows per block ----
    const int pid = bid - bid / 5 - 1;
    const int row = (pid << 2) | (tid >> 6);  // b*2048+i
    const int lane = tid & 63;
    const int* src = adj + (size_t)row * NN;
    u32* dst = bits + (size_t)row * 64;
#pragma unroll 8
    for (int it = 0; it < 32; ++it) {
      const int v = src[it * 64 + lane];
      const u64 m = __ballot(v != 0);
      if (lane == 0) *(u64*)(dst + it * 2) = m;
    }
    return;
  }

  // ---- proj role: pid in [0,512), 16 x-rows per block ----
  const int pid = bid / 5;
  const int f = tid & 127, g = tid >> 7;
  const float4* Wg4 = (const float4*)W;
  float4* Ws4 = (float4*)Ws;
#pragma unroll
  for (int t = 0; t < 16; ++t) Ws4[t * 256 + tid] = Wg4[t * 256 + tid];
  __syncthreads();

  const int rb = pid * 16 + g * 8;  // 8 rows for this half
  const int head = f >> 5, d = f & 31;
  const int b = rb >> 11, n0 = rb & (NN - 1);
  const int bh = b * NH + head;
  const float a_s = a[head * (2 * DH) + d];
  const float a_d = a[head * (2 * DH) + DH + d];

  float acc[8];
#pragma unroll
  for (int r = 0; r < 8; ++r) acc[r] = 0.f;

  const float* xb = x + (size_t)rb * FIN;  // wave-uniform -> s_loads
  for (int k = 0; k < FIN; ++k) {
    const float wv = Ws[k * 128 + f];
#pragma unroll
    for (int r = 0; r < 8; ++r) acc[r] = fmaf(wv, xb[r * FIN + k], acc[r]);
  }

  // bf16 transposed store hT[bh][d][n0..n0+8]
  u16 hs[8];
#pragma unroll
  for (int r = 0; r < 8; ++r) hs[r] = f2bf_rne(acc[r]);
  u16* dst = hT + ((size_t)bh * DH + d) * NN + n0;
  *(int4*)dst = *(int4*)&hs[0];

#pragma unroll
  for (int r = 0; r < 8; ++r) {
    float s1 = acc[r] * a_s;
    float s2 = acc[r] * a_d;
#pragma unroll
    for (int off = 16; off >= 1; off >>= 1) {
      s1 += __shfl_xor(s1, off);
      s2 += __shfl_xor(s2, off);
    }
    if (d == 0) {
      e_src[(size_t)bh * NN + n0 + r] = s1;
      e_dst[(size_t)bh * NN + n0 + r] = s2;
    }
  }
}

// ---------------- K1.5: per-bh max + P/Q tables ------------------------------
__global__ __launch_bounds__(64) void k_prep(
    const float* __restrict__ e_dst, float* __restrict__ P,
    float* __restrict__ Q, float* __restrict__ M) {
  const int bh = blockIdx.x >> 3, seg = blockIdx.x & 7;
  const int lane = threadIdx.x;
  const float* ed = e_dst + (size_t)bh * NN;
  float m = -1e30f;
#pragma unroll
  for (int t = 0; t < 32; ++t) m = fmaxf(m, ed[t * 64 + lane]);
#pragma unroll
  for (int off = 32; off >= 1; off >>= 1) m = fmaxf(m, __shfl_xor(m, off));
  if (seg == 0 && lane == 0) M[bh] = m;
#pragma unroll
  for (int t = 0; t < 4; ++t) {
    const int j = seg * 256 + t * 64 + lane;
    const float e = ed[j];
    P[(size_t)bh * NN + j] = __expf(e);
    Q[(size_t)bh * NN + j] = __expf(NS * e);
  }
}

// ---------------- K2: masked softmax weights -> MFMA -> direct output -------
__global__ __launch_bounds__(256) void k_attn(
    const u16* __restrict__ hT, const float* __restrict__ e_src,
    const float* __restrict__ Pv, const float* __restrict__ Qv,
    const float* __restrict__ Mv, const u32* __restrict__ bits,
    float* __restrict__ out) {
  __shared__ float part[4][32][33];
  __shared__ float sp[4][2][16];

  const int bid = blockIdx.x;          // 16 bh x 64 row-tiles
  const int bh = bid >> 6;
  const int it = bid & 63;
  const int b = bh >> 2, head = bh & 3;

  const int w = threadIdx.x >> 6;      // j-quarter
  const int lane = threadIdx.x & 63;
  const int lg = lane >> 4, lm = lane & 15;

  const int i0 = it * 32 + lm;         // this lane's two weight rows
  const int i1 = i0 + 16;
  const float m = Mv[bh];
  const float es0 = e_src[(size_t)bh * NN + i0];
  const float es1 = e_src[(size_t)bh * NN + i1];
  const float mr0 = es0 + m, mr1 = es1 + m;
  const float mi0 = fmaxf(mr0, NS * mr0), mi1 = fmaxf(mr1, NS * mr1);
  const float A0 = __expf(es0 - mi0), B0 = __expf(NS * es0 - mi0);
  const float A1 = __expf(es1 - mi1), B1 = __expf(NS * es1 - mi1);
  // exp monotone + lrelu(z)=max(z,0.2z)  =>  w = max(A*P_j, B*Q_j), exact.

  const float* Pb = Pv + (size_t)bh * NN;
  const float* Qb = Qv + (size_t)bh * NN;
  const u16* hb0 = hT + ((size_t)bh * DH + lm) * NN;
  const u16* hb1 = hT + ((size_t)bh * DH + 16 + lm) * NN;
  const u32* br0 = bits + ((size_t)b * NN + i0) * 64 + w * 16;
  const u32* br1 = bits + ((size_t)b * NN + i1) * 64 + w * 16;
  const int shamt = lg * 8;

  f32x4 acc00 = {0,0,0,0}, acc01 = {0,0,0,0};
  f32x4 acc10 = {0,0,0,0}, acc11 = {0,0,0,0};
  float S0 = 0.f, S1 = 0.f;

  const int jbase = w * 512 + lg * 8;
#pragma unroll 2
  for (int ch = 0; ch < 16; ++ch) {
    const int jj = jbase + ch * 32;
    const u32 wsh0 = br0[ch] >> shamt;
    const u32 wsh1 = br1[ch] >> shamt;
    const float4 p0 = *(const float4*)(Pb + jj);
    const float4 p1 = *(const float4*)(Pb + jj + 4);
    const float4 q0 = *(const float4*)(Qb + jj);
    const float4 q1 = *(const float4*)(Qb + jj + 4);
    const short8 hv0 = *(const short8*)(hb0 + jj);
    const short8 hv1 = *(const short8*)(hb1 + jj);
    const float pp[8] = {p0.x, p0.y, p0.z, p0.w, p1.x, p1.y, p1.z, p1.w};
    const float qq[8] = {q0.x, q0.y, q0.z, q0.w, q1.x, q1.y, q1.z, q1.w};
    short8 af0, af1;
#pragma unroll
    for (int e = 0; e < 8; ++e) {
      const int m0 = (int)(wsh0 << (31 - e)) >> 31;  // bit e replicated
      const int m1 = (int)(wsh1 << (31 - e)) >> 31;
      float w0 = fmaxf(A0 * pp[e], B0 * qq[e]);
      w0 = __int_as_float(__float_as_int(w0) & m0);
      S0 += w0;
      af0[e] = (short)__builtin_bit_cast(unsigned short, __float2bfloat16(w0));
      float w1 = fmaxf(A1 * pp[e], B1 * qq[e]);
      w1 = __int_as_float(__float_as_int(w1) & m1);
      S1 += w1;
      af1[e] = (short)__builtin_bit_cast(unsigned short, __float2bfloat16(w1));
    }
    __builtin_amdgcn_s_setprio(1);
    acc00 = __builtin_amdgcn_mfma_f32_16x16x32_bf16(af0, hv0, acc00, 0, 0, 0);
    acc01 = __builtin_amdgcn_mfma_f32_16x16x32_bf16(af0, hv1, acc01, 0, 0, 0);
    acc10 = __builtin_amdgcn_mfma_f32_16x16x32_bf16(af1, hv0, acc10, 0, 0, 0);
    acc11 = __builtin_amdgcn_mfma_f32_16x16x32_bf16(af1, hv1, acc11, 0, 0, 0);
    __builtin_amdgcn_s_setprio(0);
  }

  // denominator over this wave's j-quarter (sum the 4 k-groups)
  S0 += __shfl_xor(S0, 16); S0 += __shfl_xor(S0, 32);
  S1 += __shfl_xor(S1, 16); S1 += __shfl_xor(S1, 32);

#pragma unroll
  for (int r = 0; r < 4; ++r) {
    const int rl = lg * 4 + r;   // C row = (lane>>4)*4 + reg
    part[w][rl][lm] = acc00[r];
    part[w][rl][16 + lm] = acc01[r];
    part[w][16 + rl][lm] = acc10[r];
    part[w][16 + rl][16 + lm] = acc11[r];
  }
  if (lg == 0) { sp[w][0][lm] = S0; sp[w][1][lm] = S1; }
  __syncthreads();

  const int tid = threadIdx.x;
#pragma unroll
  for (int t = 0; t < 4; ++t) {
    const int idx = t * 256 + tid;
    const int row = idx >> 5, d = idx & 31;
    const float v = part[0][row][d] + part[1][row][d] +
                    part[2][row][d] + part[3][row][d];
    const float s = sp[0][row >> 4][row & 15] + sp[1][row >> 4][row & 15] +
                    sp[2][row >> 4][row & 15] + sp[3][row >> 4][row & 15];
    const float o = v / s;
    const int n = it * 32 + row;
    out[((size_t)b * NN + n) * 128 + head * 32 + d] =
        o > 0.f ? o : (__expf(o) - 1.f);
  }
}

extern "C" void kernel_launch(void* const* d_in, const int* in_sizes, int n_in,
                              void* d_out, int out_size, void* d_ws, size_t ws_size,
                              hipStream_t stream) {
  const float* x = (const float*)d_in[0];
  const int* adj = (const int*)d_in[1];
  const float* W = (const float*)d_in[2];
  const float* a = (const float*)d_in[3];
  float* out = (float*)d_out;
  float* ws = (float*)d_ws;

  float* e_src = ws + OFF_ES;
  float* e_dst = ws + OFF_ED;
  float* Pv = ws + OFF_P;
  float* Qv = ws + OFF_Q;
  float* Mv = ws + OFF_M;
  u16* hT = (u16*)(ws + OFF_HT);
  u32* bits = (u32*)(ws + OFF_BITS);

  k_pp<<<2560, 256, 0, stream>>>(adj, bits, x, W, a, hT, e_src, e_dst);
  k_prep<<<BB * NH * 8, 64, 0, stream>>>(e_dst, Pv, Qv, Mv);
  k_attn<<<BB * NH * 64, 256, 0, stream>>>(hT, e_src, Pv, Qv, Mv, bits, out);
}

// Round 7
// 88.694 us; speedup vs baseline: 1.2017x; 1.2017x over previous
//
#include <hip/hip_runtime.h>
#include <hip/hip_bf16.h>

#define BB 4
#define NN 2048
#define FIN 128
#define NH 4
#define DH 32
#define NS 0.2f

typedef unsigned int u32;
typedef unsigned short u16;
typedef unsigned long long u64;
typedef __attribute__((ext_vector_type(8))) short short8;
typedef __attribute__((ext_vector_type(4))) float f32x4;

// ws float offsets
#define OFF_ES 0          // [16][2048]
#define OFF_ED 32768      // [16][2048]
#define OFF_P  65536      // [16][2048]
#define OFF_Q  98304      // [16][2048]
#define OFF_M  131072     // [16]
#define OFF_HT 131088     // u16 [16][32][2048] = 1048576 u16 = 524288 floats
#define OFF_BITS 655376   // u32 [4][2048][64] = 524288 u32 (= OFF_HT + 524288)

__device__ __forceinline__ u16 f2bf_rne(float f) {
  unsigned u = __float_as_uint(f);
  return (u16)((u + 0x7fffu + ((u >> 16) & 1u)) >> 16);
}

// ---------------- K0: pack adj -> bitmask (0 LDS, full occupancy) -----------
__global__ __launch_bounds__(256) void k_pack(const int* __restrict__ adj,
                                              u32* __restrict__ bits) {
  const int row = (blockIdx.x << 2) | (threadIdx.x >> 6);  // 0..8191 = b*2048+i
  const int lane = threadIdx.x & 63;
  const int* src = adj + (size_t)row * NN;
  u32* dst = bits + (size_t)row * 64;
#pragma unroll 8
  for (int it = 0; it < 32; ++it) {
    const int v = src[it * 64 + lane];
    const u64 m = __ballot(v != 0);
    if (lane == 0) *(u64*)(dst + it * 2) = m;
  }
}

// ---------------- K1: projection + e_src/e_dst + bf16 transposed h ----------
__global__ __launch_bounds__(256) void k_proj(
    const float* __restrict__ x, const float* __restrict__ W,
    const float* __restrict__ a, u16* __restrict__ hT,
    float* __restrict__ e_src, float* __restrict__ e_dst) {
  __shared__ float Ws[FIN * 128];
  const int tid = threadIdx.x;
  const int f = tid & 127, g = tid >> 7;
  const float4* Wg4 = (const float4*)W;
  float4* Ws4 = (float4*)Ws;
#pragma unroll
  for (int t = 0; t < 16; ++t) Ws4[t * 256 + tid] = Wg4[t * 256 + tid];
  __syncthreads();

  const int rb = blockIdx.x * 16 + g * 8;  // 8 rows for this half
  const int head = f >> 5, d = f & 31;
  const int b = rb >> 11, n0 = rb & (NN - 1);
  const int bh = b * NH + head;
  const float a_s = a[head * (2 * DH) + d];
  const float a_d = a[head * (2 * DH) + DH + d];

  float acc[8];
#pragma unroll
  for (int r = 0; r < 8; ++r) acc[r] = 0.f;

  const float* xb = x + (size_t)rb * FIN;  // wave-uniform -> s_loads
  for (int k = 0; k < FIN; ++k) {
    const float wv = Ws[k * 128 + f];
#pragma unroll
    for (int r = 0; r < 8; ++r) acc[r] = fmaf(wv, xb[r * FIN + k], acc[r]);
  }

  // bf16 transposed store hT[bh][d][n0..n0+8]
  u16 hs[8];
#pragma unroll
  for (int r = 0; r < 8; ++r) hs[r] = f2bf_rne(acc[r]);
  u16* dst = hT + ((size_t)bh * DH + d) * NN + n0;
  *(int4*)dst = *(int4*)&hs[0];

#pragma unroll
  for (int r = 0; r < 8; ++r) {
    float s1 = acc[r] * a_s;
    float s2 = acc[r] * a_d;
#pragma unroll
    for (int off = 16; off >= 1; off >>= 1) {
      s1 += __shfl_xor(s1, off);
      s2 += __shfl_xor(s2, off);
    }
    if (d == 0) {
      e_src[(size_t)bh * NN + n0 + r] = s1;
      e_dst[(size_t)bh * NN + n0 + r] = s2;
    }
  }
}

// ---------------- K1.5: per-bh max + P/Q tables ------------------------------
__global__ __launch_bounds__(64) void k_prep(
    const float* __restrict__ e_dst, float* __restrict__ P,
    float* __restrict__ Q, float* __restrict__ M) {
  const int bh = blockIdx.x >> 3, seg = blockIdx.x & 7;
  const int lane = threadIdx.x;
  const float* ed = e_dst + (size_t)bh * NN;
  float m = -1e30f;
#pragma unroll
  for (int t = 0; t < 32; ++t) m = fmaxf(m, ed[t * 64 + lane]);
#pragma unroll
  for (int off = 32; off >= 1; off >>= 1) m = fmaxf(m, __shfl_xor(m, off));
  if (seg == 0 && lane == 0) M[bh] = m;
#pragma unroll
  for (int t = 0; t < 4; ++t) {
    const int j = seg * 256 + t * 64 + lane;
    const float e = ed[j];
    P[(size_t)bh * NN + j] = __expf(e);
    Q[(size_t)bh * NN + j] = __expf(NS * e);
  }
}

// ---------------- K2: masked softmax weights -> MFMA -> direct output -------
// 16 rows per block, 4 waves = 4 j-quarters, grid 2048 (~8 blocks/CU)
__global__ __launch_bounds__(256) void k_attn(
    const u16* __restrict__ hT, const float* __restrict__ e_src,
    const float* __restrict__ Pv, const float* __restrict__ Qv,
    const float* __restrict__ Mv, const u32* __restrict__ bits,
    float* __restrict__ out) {
  __shared__ float part[4][16][33];
  __shared__ float sp[4][16];

  const int bid = blockIdx.x;          // 16 bh x 128 row-tiles
  const int bh = bid >> 7;
  const int it = bid & 127;
  const int b = bh >> 2, head = bh & 3;

  const int w = threadIdx.x >> 6;      // j-quarter
  const int lane = threadIdx.x & 63;
  const int lg = lane >> 4, lm = lane & 15;

  const int i0 = it * 16 + lm;         // this lane's weight row
  const float m = Mv[bh];
  const float es0 = e_src[(size_t)bh * NN + i0];
  const float mr0 = es0 + m;
  const float mi0 = fmaxf(mr0, NS * mr0);   // lrelu(es+max_ed): safe shift
  const float A0 = __expf(es0 - mi0), B0 = __expf(NS * es0 - mi0);
  // exp monotone + lrelu(z)=max(z,0.2z)  =>  w = max(A*P_j, B*Q_j), exact.

  const float* Pb = Pv + (size_t)bh * NN;
  const float* Qb = Qv + (size_t)bh * NN;
  const u16* hb0 = hT + ((size_t)bh * DH + lm) * NN;
  const u16* hb1 = hT + ((size_t)bh * DH + 16 + lm) * NN;
  const u32* br0 = bits + ((size_t)b * NN + i0) * 64 + w * 16;
  const int shamt = lg * 8;

  f32x4 acc00 = {0,0,0,0}, acc01 = {0,0,0,0};
  float S0 = 0.f;

  const int jbase = w * 512 + lg * 8;
  for (int jo = 0; jo < 4; ++jo) {
    const int4 bq0 = *(const int4*)(br0 + jo * 4);
    const int wa0[4] = {bq0.x, bq0.y, bq0.z, bq0.w};
#pragma unroll
    for (int ju = 0; ju < 4; ++ju) {
      const int jj = jbase + jo * 128 + ju * 32;
      const float4 p0 = *(const float4*)(Pb + jj);
      const float4 p1 = *(const float4*)(Pb + jj + 4);
      const float4 q0 = *(const float4*)(Qb + jj);
      const float4 q1 = *(const float4*)(Qb + jj + 4);
      const short8 hv0 = *(const short8*)(hb0 + jj);
      const short8 hv1 = *(const short8*)(hb1 + jj);
      const u32 wsh0 = ((u32)wa0[ju]) >> shamt;
      const float pp[8] = {p0.x, p0.y, p0.z, p0.w, p1.x, p1.y, p1.z, p1.w};
      const float qq[8] = {q0.x, q0.y, q0.z, q0.w, q1.x, q1.y, q1.z, q1.w};
      short8 af0;
#pragma unroll
      for (int e = 0; e < 8; ++e) {
        const int m0 = (int)(wsh0 << (31 - e)) >> 31;  // bit e replicated
        float w0 = fmaxf(A0 * pp[e], B0 * qq[e]);
        w0 = __int_as_float(__float_as_int(w0) & m0);
        S0 += w0;
        af0[e] = (short)__builtin_bit_cast(unsigned short, __float2bfloat16(w0));
      }
      __builtin_amdgcn_s_setprio(1);
      acc00 = __builtin_amdgcn_mfma_f32_16x16x32_bf16(af0, hv0, acc00, 0, 0, 0);
      acc01 = __builtin_amdgcn_mfma_f32_16x16x32_bf16(af0, hv1, acc01, 0, 0, 0);
      __builtin_amdgcn_s_setprio(0);
    }
  }

  // denominator for row lm over this wave's j-quarter (sum the 4 k-groups)
  S0 += __shfl_xor(S0, 16);
  S0 += __shfl_xor(S0, 32);

#pragma unroll
  for (int r = 0; r < 4; ++r) {
    const int rl = lg * 4 + r;   // C row = (lane>>4)*4 + reg
    part[w][rl][lm] = acc00[r];
    part[w][rl][16 + lm] = acc01[r];
  }
  if (lg == 0) sp[w][lm] = S0;
  __syncthreads();

  const int tid = threadIdx.x;
#pragma unroll
  for (int t = 0; t < 2; ++t) {
    const int idx = t * 256 + tid;
    const int row = idx >> 5, d = idx & 31;
    const float v = part[0][row][d] + part[1][row][d] +
                    part[2][row][d] + part[3][row][d];
    const float s = sp[0][row] + sp[1][row] + sp[2][row] + sp[3][row];
    const float o = v / s;
    const int n = it * 16 + row;
    out[((size_t)b * NN + n) * 128 + head * 32 + d] =
        o > 0.f ? o : (__expf(o) - 1.f);
  }
}

extern "C" void kernel_launch(void* const* d_in, const int* in_sizes, int n_in,
                              void* d_out, int out_size, void* d_ws, size_t ws_size,
                              hipStream_t stream) {
  const float* x = (const float*)d_in[0];
  const int* adj = (const int*)d_in[1];
  const float* W = (const float*)d_in[2];
  const float* a = (const float*)d_in[3];
  float* out = (float*)d_out;
  float* ws = (float*)d_ws;

  float* e_src = ws + OFF_ES;
  float* e_dst = ws + OFF_ED;
  float* Pv = ws + OFF_P;
  float* Qv = ws + OFF_Q;
  float* Mv = ws + OFF_M;
  u16* hT = (u16*)(ws + OFF_HT);
  u32* bits = (u32*)(ws + OFF_BITS);

  k_pack<<<(BB * NN) / 4, 256, 0, stream>>>(adj, bits);
  k_proj<<<(BB * NN) / 16, 256, 0, stream>>>(x, W, a, hT, e_src, e_dst);
  k_prep<<<BB * NH * 8, 64, 0, stream>>>(e_dst, Pv, Qv, Mv);
  k_attn<<<BB * NH * 128, 256, 0, stream>>>(hT, e_src, Pv, Qv, Mv, bits, out);
}

// Round 8
// 64.789 us; speedup vs baseline: 1.6452x; 1.3690x over previous
//
#include <hip/hip_runtime.h>
#include <hip/hip_bf16.h>

#define BB 4
#define NN 2048
#define FIN 128
#define NH 4
#define DH 32
#define NS 0.2f

typedef unsigned int u32;
typedef unsigned short u16;
typedef unsigned long long u64;
typedef __attribute__((ext_vector_type(8))) short short8;
typedef __attribute__((ext_vector_type(4))) float f32x4;
typedef __attribute__((ext_vector_type(4))) unsigned int u32x4;

// ws float offsets
#define OFF_ES 0          // [16][2048] f32
#define OFF_ED 32768      // [16][2048] f32
#define OFF_PQ 65536      // [16][2048] u32 (bf16 Q hi | bf16 P lo)
#define OFF_M  131072     // [16]
#define OFF_HT 131088     // u16 [16][32][2048] = 1048576 u16 = 524288 floats
#define OFF_BITS 655376   // u32 [4][2048][64] = 524288 u32

__device__ __forceinline__ u16 f2bf_rne(float f) {
  unsigned u = __float_as_uint(f);
  return (u16)((u + 0x7fffu + ((u >> 16) & 1u)) >> 16);
}

__device__ __forceinline__ int sign_bit(u32 w, int e) {
#if __has_builtin(__builtin_amdgcn_sbfe)
  return __builtin_amdgcn_sbfe((int)w, e, 1);
#else
  return ((int)(w << (31 - e))) >> 31;
#endif
}

// ---------------- K0: pack adj -> bitmask (0 LDS, full occupancy) -----------
__global__ __launch_bounds__(256) void k_pack(const int* __restrict__ adj,
                                              u32* __restrict__ bits) {
  const int row = (blockIdx.x << 2) | (threadIdx.x >> 6);  // b*2048+i
  const int lane = threadIdx.x & 63;
  const int* src = adj + (size_t)row * NN;
  u32* dst = bits + (size_t)row * 64;
#pragma unroll 8
  for (int it = 0; it < 32; ++it) {
    const int v = src[it * 64 + lane];
    const u64 m = __ballot(v != 0);
    if (lane == 0) *(u64*)(dst + it * 2) = m;
  }
}

// ---------------- K1: projection + e_src/e_dst + bf16 transposed h ----------
__global__ __launch_bounds__(256) void k_proj(
    const float* __restrict__ x, const float* __restrict__ W,
    const float* __restrict__ a, u16* __restrict__ hT,
    float* __restrict__ e_src, float* __restrict__ e_dst) {
  __shared__ float Ws[FIN * 128];
  const int tid = threadIdx.x;
  const int f = tid & 127, g = tid >> 7;
  const float4* Wg4 = (const float4*)W;
  float4* Ws4 = (float4*)Ws;
#pragma unroll
  for (int t = 0; t < 16; ++t) Ws4[t * 256 + tid] = Wg4[t * 256 + tid];
  __syncthreads();

  const int rb = blockIdx.x * 16 + g * 8;
  const int head = f >> 5, d = f & 31;
  const int b = rb >> 11, n0 = rb & (NN - 1);
  const int bh = b * NH + head;
  const float a_s = a[head * (2 * DH) + d];
  const float a_d = a[head * (2 * DH) + DH + d];

  float acc[8];
#pragma unroll
  for (int r = 0; r < 8; ++r) acc[r] = 0.f;

  const float* xb = x + (size_t)rb * FIN;
  for (int k = 0; k < FIN; ++k) {
    const float wv = Ws[k * 128 + f];
#pragma unroll
    for (int r = 0; r < 8; ++r) acc[r] = fmaf(wv, xb[r * FIN + k], acc[r]);
  }

  u16 hs[8];
#pragma unroll
  for (int r = 0; r < 8; ++r) hs[r] = f2bf_rne(acc[r]);
  u16* dst = hT + ((size_t)bh * DH + d) * NN + n0;
  *(int4*)dst = *(int4*)&hs[0];

#pragma unroll
  for (int r = 0; r < 8; ++r) {
    float s1 = acc[r] * a_s;
    float s2 = acc[r] * a_d;
#pragma unroll
    for (int off = 16; off >= 1; off >>= 1) {
      s1 += __shfl_xor(s1, off);
      s2 += __shfl_xor(s2, off);
    }
    if (d == 0) {
      e_src[(size_t)bh * NN + n0 + r] = s1;
      e_dst[(size_t)bh * NN + n0 + r] = s2;
    }
  }
}

// ---------------- K1.5: per-bh max + packed bf16 P/Q table ------------------
__global__ __launch_bounds__(64) void k_prep(
    const float* __restrict__ e_dst, u32* __restrict__ PQ,
    float* __restrict__ M) {
  const int bh = blockIdx.x >> 3, seg = blockIdx.x & 7;
  const int lane = threadIdx.x;
  const float* ed = e_dst + (size_t)bh * NN;
  float m = -1e30f;
#pragma unroll
  for (int t = 0; t < 32; ++t) m = fmaxf(m, ed[t * 64 + lane]);
#pragma unroll
  for (int off = 32; off >= 1; off >>= 1) m = fmaxf(m, __shfl_xor(m, off));
  if (seg == 0 && lane == 0) M[bh] = m;
#pragma unroll
  for (int t = 0; t < 4; ++t) {
    const int j = seg * 256 + t * 64 + lane;
    const float e = ed[j];
    const u32 pb = f2bf_rne(__expf(e));
    const u32 qb = f2bf_rne(__expf(NS * e));
    PQ[(size_t)bh * NN + j] = (qb << 16) | pb;
  }
}

// ---------------- K2: weights -> MFMA -> direct output ----------------------
// 32 rows/block (two 16-row sets), 4 waves = 4 j-quarters, grid 1024.
// Explicit 1-deep register pipeline on the PQ/hT streams.
__global__ __launch_bounds__(256) void k_attn(
    const u16* __restrict__ hT, const float* __restrict__ e_src,
    const u32* __restrict__ PQv, const float* __restrict__ Mv,
    const u32* __restrict__ bits, float* __restrict__ out) {
  __shared__ float part[4][32][33];
  __shared__ float sp[4][2][16];

  const int bid = blockIdx.x;          // 16 bh x 64 row-tiles
  const int bh = bid >> 6;
  const int it = bid & 63;
  const int b = bh >> 2, head = bh & 3;

  const int w = threadIdx.x >> 6;      // j-quarter
  const int lane = threadIdx.x & 63;
  const int lg = lane >> 4, lm = lane & 15;

  const int i0 = it * 32 + lm;
  const int i1 = i0 + 16;
  const float m = Mv[bh];
  const float es0 = e_src[(size_t)bh * NN + i0];
  const float es1 = e_src[(size_t)bh * NN + i1];
  const float mr0 = es0 + m, mr1 = es1 + m;
  const float mi0 = fmaxf(mr0, NS * mr0), mi1 = fmaxf(mr1, NS * mr1);
  const float A0 = __expf(es0 - mi0), B0 = __expf(NS * es0 - mi0);
  const float A1 = __expf(es1 - mi1), B1 = __expf(NS * es1 - mi1);
  // w = exp(lrelu(es+ed)-mi) = max(A*P_j, B*Q_j)   (exp monotone, exact)

  const u32* PQb = PQv + (size_t)bh * NN;
  const u16* hb0 = hT + ((size_t)bh * DH + lm) * NN;
  const u16* hb1 = hT + ((size_t)bh * DH + 16 + lm) * NN;
  const u32* br0 = bits + ((size_t)b * NN + i0) * 64 + w * 16;
  const u32* br1 = bits + ((size_t)b * NN + i1) * 64 + w * 16;
  const int shamt = lg * 8;

  // hoist all bit-words for this wave's j-quarter (8 x int4 = 32 u32)
  u32 wd0[16], wd1[16];
#pragma unroll
  for (int jo = 0; jo < 4; ++jo) {
    const u32x4 v0 = *(const u32x4*)(br0 + jo * 4);
    const u32x4 v1 = *(const u32x4*)(br1 + jo * 4);
#pragma unroll
    for (int k = 0; k < 4; ++k) { wd0[jo * 4 + k] = v0[k]; wd1[jo * 4 + k] = v1[k]; }
  }

  f32x4 acc00 = {0,0,0,0}, acc01 = {0,0,0,0};
  f32x4 acc10 = {0,0,0,0}, acc11 = {0,0,0,0};
  float S0 = 0.f, S1 = 0.f;

  const int jbase = w * 512 + lg * 8;

  // prologue loads (chunk 0)
  u32x4 pqa_c = *(const u32x4*)(PQb + jbase);
  u32x4 pqb_c = *(const u32x4*)(PQb + jbase + 4);
  short8 h0_c = *(const short8*)(hb0 + jbase);
  short8 h1_c = *(const short8*)(hb1 + jbase);

#pragma unroll
  for (int c = 0; c < 16; ++c) {
    u32x4 pqa_n, pqb_n; short8 h0_n, h1_n;
    if (c < 15) {
      const int jn = jbase + (c + 1) * 32;
      pqa_n = *(const u32x4*)(PQb + jn);
      pqb_n = *(const u32x4*)(PQb + jn + 4);
      h0_n = *(const short8*)(hb0 + jn);
      h1_n = *(const short8*)(hb1 + jn);
    }
    const u32 wsh0 = wd0[c] >> shamt;
    const u32 wsh1 = wd1[c] >> shamt;
    short8 af0, af1;
#pragma unroll
    for (int e = 0; e < 8; ++e) {
      const u32 pq = (e < 4) ? pqa_c[e] : pqb_c[e - 4];
      const float Pf = __uint_as_float(pq << 16);
      const float Qf = __uint_as_float(pq & 0xffff0000u);
      const int m0 = sign_bit(wsh0, e);
      const int m1 = sign_bit(wsh1, e);
      float w0 = fmaxf(A0 * Pf, B0 * Qf);
      w0 = __int_as_float(__float_as_int(w0) & m0);
      S0 += w0;
      af0[e] = (short)__builtin_bit_cast(unsigned short, __float2bfloat16(w0));
      float w1 = fmaxf(A1 * Pf, B1 * Qf);
      w1 = __int_as_float(__float_as_int(w1) & m1);
      S1 += w1;
      af1[e] = (short)__builtin_bit_cast(unsigned short, __float2bfloat16(w1));
    }
    __builtin_amdgcn_s_setprio(1);
    acc00 = __builtin_amdgcn_mfma_f32_16x16x32_bf16(af0, h0_c, acc00, 0, 0, 0);
    acc01 = __builtin_amdgcn_mfma_f32_16x16x32_bf16(af0, h1_c, acc01, 0, 0, 0);
    acc10 = __builtin_amdgcn_mfma_f32_16x16x32_bf16(af1, h0_c, acc10, 0, 0, 0);
    acc11 = __builtin_amdgcn_mfma_f32_16x16x32_bf16(af1, h1_c, acc11, 0, 0, 0);
    __builtin_amdgcn_s_setprio(0);
    if (c < 15) { pqa_c = pqa_n; pqb_c = pqb_n; h0_c = h0_n; h1_c = h1_n; }
  }

  S0 += __shfl_xor(S0, 16); S0 += __shfl_xor(S0, 32);
  S1 += __shfl_xor(S1, 16); S1 += __shfl_xor(S1, 32);

#pragma unroll
  for (int r = 0; r < 4; ++r) {
    const int rl = lg * 4 + r;   // C row = (lane>>4)*4 + reg
    part[w][rl][lm] = acc00[r];
    part[w][rl][16 + lm] = acc01[r];
    part[w][16 + rl][lm] = acc10[r];
    part[w][16 + rl][16 + lm] = acc11[r];
  }
  if (lg == 0) { sp[w][0][lm] = S0; sp[w][1][lm] = S1; }
  __syncthreads();

  const int tid = threadIdx.x;
#pragma unroll
  for (int t = 0; t < 4; ++t) {
    const int idx = t * 256 + tid;
    const int row = idx >> 5, d = idx & 31;
    const float v = part[0][row][d] + part[1][row][d] +
                    part[2][row][d] + part[3][row][d];
    const float s = sp[0][row >> 4][row & 15] + sp[1][row >> 4][row & 15] +
                    sp[2][row >> 4][row & 15] + sp[3][row >> 4][row & 15];
    const float o = v / s;
    const int n = it * 32 + row;
    out[((size_t)b * NN + n) * 128 + head * 32 + d] =
        o > 0.f ? o : (__expf(o) - 1.f);
  }
}

extern "C" void kernel_launch(void* const* d_in, const int* in_sizes, int n_in,
                              void* d_out, int out_size, void* d_ws, size_t ws_size,
                              hipStream_t stream) {
  const float* x = (const float*)d_in[0];
  const int* adj = (const int*)d_in[1];
  const float* W = (const float*)d_in[2];
  const float* a = (const float*)d_in[3];
  float* out = (float*)d_out;
  float* ws = (float*)d_ws;

  float* e_src = ws + OFF_ES;
  float* e_dst = ws + OFF_ED;
  u32* PQv = (u32*)(ws + OFF_PQ);
  float* Mv = ws + OFF_M;
  u16* hT = (u16*)(ws + OFF_HT);
  u32* bits = (u32*)(ws + OFF_BITS);

  k_pack<<<(BB * NN) / 4, 256, 0, stream>>>(adj, bits);
  k_proj<<<(BB * NN) / 16, 256, 0, stream>>>(x, W, a, hT, e_src, e_dst);
  k_prep<<<BB * NH * 8, 64, 0, stream>>>(e_dst, PQv, Mv);
  k_attn<<<BB * NH * 64, 256, 0, stream>>>(hT, e_src, PQv, Mv, bits, out);
}

// Round 10
// 62.433 us; speedup vs baseline: 1.7072x; 1.0377x over previous
//
#include <hip/hip_runtime.h>
#include <hip/hip_bf16.h>

#define BB 4
#define NN 2048
#define FIN 128
#define NH 4
#define DH 32
#define NS 0.2f

typedef unsigned int u32;
typedef unsigned short u16;
typedef unsigned long long u64;
typedef __attribute__((ext_vector_type(8))) short short8;
typedef __attribute__((ext_vector_type(4))) float f32x4;
typedef __attribute__((ext_vector_type(4))) unsigned int u32x4;

// ws float offsets
#define OFF_ES 0          // [16][2048] f32
#define OFF_ED 32768      // [16][2048] f32
#define OFF_PQ 65536      // [16][2048] u32 (bf16 Q hi | bf16 P lo)
#define OFF_M  131072     // [16]
#define OFF_HT 131088     // u16 [16][32][2048] = 1048576 u16 = 524288 floats
#define OFF_BITS 655376   // u32 [4][2048][64] = 524288 u32

__device__ __forceinline__ u16 f2bf_rne(float f) {
  unsigned u = __float_as_uint(f);
  return (u16)((u + 0x7fffu + ((u >> 16) & 1u)) >> 16);
}

// ---------------- K0: pack adj -> bitmask (0 LDS, full occupancy) -----------
__global__ __launch_bounds__(256) void k_pack(const int* __restrict__ adj,
                                              u32* __restrict__ bits) {
  const int row = (blockIdx.x << 2) | (threadIdx.x >> 6);  // b*2048+i
  const int lane = threadIdx.x & 63;
  const int* src = adj + (size_t)row * NN;
  u32* dst = bits + (size_t)row * 64;
#pragma unroll 8
  for (int it = 0; it < 32; ++it) {
    const int v = src[it * 64 + lane];
    const u64 m = __ballot(v != 0);
    if (lane == 0) *(u64*)(dst + it * 2) = m;
  }
}

// ---------------- K1: projection + e_src/e_dst + bf16 transposed h ----------
__global__ __launch_bounds__(256) void k_proj(
    const float* __restrict__ x, const float* __restrict__ W,
    const float* __restrict__ a, u16* __restrict__ hT,
    float* __restrict__ e_src, float* __restrict__ e_dst) {
  __shared__ float Ws[FIN * 128];
  const int tid = threadIdx.x;
  const int f = tid & 127, g = tid >> 7;
  const float4* Wg4 = (const float4*)W;
  float4* Ws4 = (float4*)Ws;
#pragma unroll
  for (int t = 0; t < 16; ++t) Ws4[t * 256 + tid] = Wg4[t * 256 + tid];
  __syncthreads();

  const int rb = blockIdx.x * 16 + g * 8;
  const int head = f >> 5, d = f & 31;
  const int b = rb >> 11, n0 = rb & (NN - 1);
  const int bh = b * NH + head;
  const float a_s = a[head * (2 * DH) + d];
  const float a_d = a[head * (2 * DH) + DH + d];

  float acc[8];
#pragma unroll
  for (int r = 0; r < 8; ++r) acc[r] = 0.f;

  const float* xb = x + (size_t)rb * FIN;
  for (int k = 0; k < FIN; ++k) {
    const float wv = Ws[k * 128 + f];
#pragma unroll
    for (int r = 0; r < 8; ++r) acc[r] = fmaf(wv, xb[r * FIN + k], acc[r]);
  }

  u16 hs[8];
#pragma unroll
  for (int r = 0; r < 8; ++r) hs[r] = f2bf_rne(acc[r]);
  u16* dst = hT + ((size_t)bh * DH + d) * NN + n0;
  *(int4*)dst = *(int4*)&hs[0];

#pragma unroll
  for (int r = 0; r < 8; ++r) {
    float s1 = acc[r] * a_s;
    float s2 = acc[r] * a_d;
#pragma unroll
    for (int off = 16; off >= 1; off >>= 1) {
      s1 += __shfl_xor(s1, off);
      s2 += __shfl_xor(s2, off);
    }
    if (d == 0) {
      e_src[(size_t)bh * NN + n0 + r] = s1;
      e_dst[(size_t)bh * NN + n0 + r] = s2;
    }
  }
}

// ---------------- K1.5: per-bh max + packed bf16 P/Q table ------------------
__global__ __launch_bounds__(64) void k_prep(
    const float* __restrict__ e_dst, u32* __restrict__ PQ,
    float* __restrict__ M) {
  const int bh = blockIdx.x >> 3, seg = blockIdx.x & 7;
  const int lane = threadIdx.x;
  const float* ed = e_dst + (size_t)bh * NN;
  float m = -1e30f;
#pragma unroll
  for (int t = 0; t < 32; ++t) m = fmaxf(m, ed[t * 64 + lane]);
#pragma unroll
  for (int off = 32; off >= 1; off >>= 1) m = fmaxf(m, __shfl_xor(m, off));
  if (seg == 0 && lane == 0) M[bh] = m;
#pragma unroll
  for (int t = 0; t < 4; ++t) {
    const int j = seg * 256 + t * 64 + lane;
    const float e = ed[j];
    const u32 pb = f2bf_rne(__expf(e));
    const u32 qb = f2bf_rne(__expf(NS * e));
    PQ[(size_t)bh * NN + j] = (qb << 16) | pb;
  }
}

// ---------------- K2: LDS-staged weights->MFMA->direct output ---------------
// 32 rows/block, 4 waves = 4 j-quarters, grid 1024. hT staged through
// wave-private LDS (coalesced global loads, XOR-swizzled tile, no barriers).
__global__ __launch_bounds__(256) void k_attn(
    const u16* __restrict__ hT, const float* __restrict__ e_src,
    const u32* __restrict__ PQv, const float* __restrict__ Mv,
    const u32* __restrict__ bits, float* __restrict__ out) {
  // [wave][dbuf][32 d][64 j] u16 = 32 KB; epilogue part/sp aliased on top.
  __shared__ __align__(16) u16 smem[4][2][32 * 64];

  const int bid = blockIdx.x;          // 16 bh x 64 row-tiles
  const int bh = bid >> 6;
  const int it = bid & 63;
  const int b = bh >> 2, head = bh & 3;

  const int w = threadIdx.x >> 6;      // j-quarter
  const int lane = threadIdx.x & 63;
  const int lg = lane >> 4, lm = lane & 15;

  const int i0 = it * 32 + lm;
  const int i1 = i0 + 16;
  const float m = Mv[bh];
  const float es0 = e_src[(size_t)bh * NN + i0];
  const float es1 = e_src[(size_t)bh * NN + i1];
  const float mr0 = es0 + m, mr1 = es1 + m;
  const float mi0 = fmaxf(mr0, NS * mr0), mi1 = fmaxf(mr1, NS * mr1);
  const float A0 = __expf(es0 - mi0), B0 = __expf(NS * es0 - mi0);
  const float A1 = __expf(es1 - mi1), B1 = __expf(NS * es1 - mi1);
  // w = exp(lrelu(es+ed)-mi) = max(A*P_j, B*Q_j)   (exp monotone, exact)

  const u32* PQb = PQv + (size_t)bh * NN + w * 512;
  const u16* hb = hT + (size_t)bh * DH * NN + w * 512;   // [d][j-quarter]
  const u32* br0 = bits + ((size_t)b * NN + i0) * 64 + w * 16;
  const u32* br1 = bits + ((size_t)b * NN + i1) * 64 + w * 16;
  const int shamt = lg * 8;

  // staging lane roles: instr t loads data rows d = t*8+sd, 16B at j-offset sj.
  // LDS row == data row: store t at (sd*64 + sj)^swz + t*512  (512 u16 = 8 rows)
  const int sd = lane >> 3;
  const int sj = (lane & 7) * 8;
  u16* stg0 = &smem[w][0][0];
  u16* stg1 = &smem[w][1][0];
  const int woff = (sd * 64 + sj) ^ (sd << 3);   // row sd, swizzle (d&7)<<3

  f32x4 acc00 = {0,0,0,0}, acc01 = {0,0,0,0};
  f32x4 acc10 = {0,0,0,0}, acc11 = {0,0,0,0};
  float S0 = 0.f, S1 = 0.f;

  // prologue: stage superchunk 0
  {
    int4 r0 = *(const int4*)(hb + (size_t)(0 * 8 + sd) * NN + sj);
    int4 r1 = *(const int4*)(hb + (size_t)(1 * 8 + sd) * NN + sj);
    int4 r2 = *(const int4*)(hb + (size_t)(2 * 8 + sd) * NN + sj);
    int4 r3 = *(const int4*)(hb + (size_t)(3 * 8 + sd) * NN + sj);
    *(int4*)(stg0 + woff) = r0;
    *(int4*)(stg0 + woff + 1 * 512) = r1;
    *(int4*)(stg0 + woff + 2 * 512) = r2;
    *(int4*)(stg0 + woff + 3 * 512) = r3;
  }

  const int ra0 = (lm * 64) ^ ((lm & 7) << 3);  // swizzled base for d=lm row

#pragma unroll
  for (int s = 0; s < 8; ++s) {
    u16* cur = (s & 1) ? stg1 : stg0;
    u16* nxt = (s & 1) ? stg0 : stg1;
    int4 n0, n1, n2, n3;
    if (s < 7) {  // issue next superchunk's coalesced loads early (T14)
      const u16* g = hb + (s + 1) * 64;
      n0 = *(const int4*)(g + (size_t)(0 * 8 + sd) * NN + sj);
      n1 = *(const int4*)(g + (size_t)(1 * 8 + sd) * NN + sj);
      n2 = *(const int4*)(g + (size_t)(2 * 8 + sd) * NN + sj);
      n3 = *(const int4*)(g + (size_t)(3 * 8 + sd) * NN + sj);
    }
    const u64 wb0 = *(const u64*)(br0 + s * 2);
    const u64 wb1 = *(const u64*)(br1 + s * 2);
#pragma unroll
    for (int c = 0; c < 2; ++c) {
      const int jl = c * 32 + lg * 8;
      const u32x4 pqa = *(const u32x4*)(PQb + s * 64 + jl);
      const u32x4 pqb = *(const u32x4*)(PQb + s * 64 + jl + 4);
      const short8 hv0 = *(const short8*)(cur + (ra0 ^ jl));   // jl bits 3..5
      const short8 hv1 = *(const short8*)(cur + ((ra0 ^ jl) + 16 * 64));
      const u32 wsh0 = ((u32)(wb0 >> (c * 32))) >> shamt;
      const u32 wsh1 = ((u32)(wb1 >> (c * 32))) >> shamt;
      short8 af0, af1;
#pragma unroll
      for (int e = 0; e < 8; ++e) {
        const u32 pq = (e < 4) ? pqa[e] : pqb[e - 4];
        const float Pf = __uint_as_float(pq << 16);
        const float Qf = __uint_as_float(pq & 0xffff0000u);
        const int m0 = ((int)(wsh0 << (31 - e))) >> 31;
        const int m1 = ((int)(wsh1 << (31 - e))) >> 31;
        float w0 = fmaxf(A0 * Pf, B0 * Qf);
        w0 = __int_as_float(__float_as_int(w0) & m0);
        S0 += w0;
        af0[e] = (short)__builtin_bit_cast(unsigned short, __float2bfloat16(w0));
        float w1 = fmaxf(A1 * Pf, B1 * Qf);
        w1 = __int_as_float(__float_as_int(w1) & m1);
        S1 += w1;
        af1[e] = (short)__builtin_bit_cast(unsigned short, __float2bfloat16(w1));
      }
      __builtin_amdgcn_s_setprio(1);
      acc00 = __builtin_amdgcn_mfma_f32_16x16x32_bf16(af0, hv0, acc00, 0, 0, 0);
      acc01 = __builtin_amdgcn_mfma_f32_16x16x32_bf16(af0, hv1, acc01, 0, 0, 0);
      acc10 = __builtin_amdgcn_mfma_f32_16x16x32_bf16(af1, hv0, acc10, 0, 0, 0);
      acc11 = __builtin_amdgcn_mfma_f32_16x16x32_bf16(af1, hv1, acc11, 0, 0, 0);
      __builtin_amdgcn_s_setprio(0);
    }
    if (s < 7) {  // wave-private dbuf: no barrier needed
      *(int4*)(nxt + woff) = n0;
      *(int4*)(nxt + woff + 1 * 512) = n1;
      *(int4*)(nxt + woff + 2 * 512) = n2;
      *(int4*)(nxt + woff + 3 * 512) = n3;
    }
  }

  S0 += __shfl_xor(S0, 16); S0 += __shfl_xor(S0, 32);
  S1 += __shfl_xor(S1, 16); S1 += __shfl_xor(S1, 32);

  // epilogue combine: alias part/sp onto the (now dead) staging LDS
  __syncthreads();
  float (*part)[32][33] = (float (*)[32][33]) & smem[0][0][0];  // 16896 B
  float (*sp)[2][16] = (float (*)[2][16])((char*)&smem[0][0][0] + 16896);

#pragma unroll
  for (int r = 0; r < 4; ++r) {
    const int rl = lg * 4 + r;   // C row = (lane>>4)*4 + reg
    part[w][rl][lm] = acc00[r];
    part[w][rl][16 + lm] = acc01[r];
    part[w][16 + rl][lm] = acc10[r];
    part[w][16 + rl][16 + lm] = acc11[r];
  }
  if (lg == 0) { sp[w][0][lm] = S0; sp[w][1][lm] = S1; }
  __syncthreads();

  const int tid = threadIdx.x;
#pragma unroll
  for (int t = 0; t < 4; ++t) {
    const int idx = t * 256 + tid;
    const int row = idx >> 5, d = idx & 31;
    const float v = part[0][row][d] + part[1][row][d] +
                    part[2][row][d] + part[3][row][d];
    const float s = sp[0][row >> 4][row & 15] + sp[1][row >> 4][row & 15] +
                    sp[2][row >> 4][row & 15] + sp[3][row >> 4][row & 15];
    const float o = v / s;
    const int n = it * 32 + row;
    out[((size_t)b * NN + n) * 128 + head * 32 + d] =
        o > 0.f ? o : (__expf(o) - 1.f);
  }
}

extern "C" void kernel_launch(void* const* d_in, const int* in_sizes, int n_in,
                              void* d_out, int out_size, void* d_ws, size_t ws_size,
                              hipStream_t stream) {
  const float* x = (const float*)d_in[0];
  const int* adj = (const int*)d_in[1];
  const float* W = (const float*)d_in[2];
  const float* a = (const float*)d_in[3];
  float* out = (float*)d_out;
  float* ws = (float*)d_ws;

  float* e_src = ws + OFF_ES;
  float* e_dst = ws + OFF_ED;
  u32* PQv = (u32*)(ws + OFF_PQ);
  float* Mv = ws + OFF_M;
  u16* hT = (u16*)(ws + OFF_HT);
  u32* bits = (u32*)(ws + OFF_BITS);

  k_pack<<<(BB * NN) / 4, 256, 0, stream>>>(adj, bits);
  k_proj<<<(BB * NN) / 16, 256, 0, stream>>>(x, W, a, hT, e_src, e_dst);
  k_prep<<<BB * NH * 8, 64, 0, stream>>>(e_dst, PQv, Mv);
  k_attn<<<BB * NH * 64, 256, 0, stream>>>(hT, e_src, PQv, Mv, bits, out);
}